// Round 3
// baseline (446.596 us; speedup 1.0000x reference)
//
#include <hip/hip_runtime.h>

#define N_NODES 20000
#define WCB_FLOATS (3*9*30*64)         // 51840 = repacked W_chem (wbody folded in)
#define NAB_FLOATS (N_NODES*32)        // 30 used per node, padded to 32

// ---------------------------------------------------------------------------
// Compile-time Wigner table (R6, unchanged): identical algorithm to the
// reference, evaluated as constexpr fp64; coefficients inlined as literals.
// ---------------------------------------------------------------------------
struct kx { double re, im; };

__host__ __device__ constexpr kx kmul(kx a, kx b){
  return { a.re*b.re - a.im*b.im, a.re*b.im + a.im*b.re };
}

__host__ __device__ constexpr double cfact(int n){
  double r = 1.0; for (int i = 2; i <= n; ++i) r *= (double)i; return r;
}

__host__ __device__ constexpr double csqrt(double x){
  if (x <= 0.0) return 0.0;
  double g = x > 1.0 ? x : 1.0;
  for (int i = 0; i < 64; ++i) g = 0.5*(g + x/g);   // converged fixed point
  return g;
}

__host__ __device__ constexpr double ccg(int j1,int m1,int j2,int m2,int j3,int m3){
  if (m3 != m1 + m2) return 0.0;
  int vmin = -j1 + j2 + m3;
  if (-j1 + m1 > vmin) vmin = -j1 + m1;
  if (vmin < 0) vmin = 0;
  int vmax = j2 + j3 + m1;
  if (j3 - j1 + j2 < vmax) vmax = j3 - j1 + j2;
  if (j3 + m3 < vmax) vmax = j3 + m3;
  double c = csqrt((double)(2*j3+1) *
      (cfact(j3+j1-j2)*cfact(j3-j1+j2)*cfact(j1+j2-j3)*cfact(j3+m3)*cfact(j3-m3)) /
      (cfact(j1+j2+j3+1)*cfact(j1-m1)*cfact(j1+m1)*cfact(j2-m2)*cfact(j2+m2)));
  double s = 0.0;
  for (int v = vmin; v <= vmax; ++v){
    double t = (cfact(j2+j3+m1-v)*cfact(j1-m1+v)) /
               (cfact(v)*cfact(j3-j1+j2-v)*cfact(j3+m3-v)*cfact(v+j1-j2-m3));
    s += ((v + j2 + m2) & 1) ? -t : t;
  }
  return c * s;
}

__host__ __device__ constexpr kx cq(int l, int r, int c){
  kx v = {0.0, 0.0};
  const double is2 = 0.70710678118654752440;
  const int m = r - l;
  if (m < 0){
    if (c == 2*l - r)      v = { is2, 0.0 };
    else if (c == r)       v = { 0.0, -is2 };
  } else if (m == 0){
    if (c == l)            v = { 1.0, 0.0 };
  } else {
    const double sg = (m & 1) ? -1.0 : 1.0;
    if (c == r)            v = { sg*is2, 0.0 };
    else if (c == 2*l - r) v = { 0.0, sg*is2 };
  }
  if (l == 1)      v = { v.im, -v.re };   // * (-i)
  else if (l == 2) v = { -v.re, -v.im };  // * (-i)^2 = -1
  return v;
}

__host__ __device__ constexpr double cw_entry(int L, int M, int S){
  const int l1 = (L==0)?0:((L<4)?1:2);
  const int l2 = (M==0)?0:((M<4)?1:2);
  const int l3 = (S==0)?0:((S<4)?1:2);
  const int a  = L - ((l1==0)?0:((l1==1)?1:4));
  const int b  = M - ((l2==0)?0:((l2==1)?1:4));
  const int cc = S - ((l3==0)?0:((l3==1)?1:4));
  const int lo = (l1 > l2) ? l1 - l2 : l2 - l1;
  if (!(l3 >= lo && l3 <= l1 + l2 && (((l1 + l2 + l3) & 1) == 0))) return 0.0;
  double ar = 0.0, ai = 0.0;
  for (int i = 0; i < 2*l1+1; ++i){
    kx q1 = cq(l1, i, a);
    if (q1.re == 0.0 && q1.im == 0.0) continue;
    for (int k = 0; k < 2*l2+1; ++k){
      kx q2 = cq(l2, k, b);
      if (q2.re == 0.0 && q2.im == 0.0) continue;
      kx q12 = kmul(q1, q2);
      for (int n = 0; n < 2*l3+1; ++n){
        kx q3 = cq(l3, n, cc);
        if (q3.re == 0.0 && q3.im == 0.0) continue;
        double cg = ccg(l1, i-l1, l2, k-l2, l3, n-l3);
        if (cg == 0.0) continue;
        kx q3c = { q3.re, -q3.im };
        kx term = kmul(q12, q3c);
        ar += term.re * cg;
        ai += term.im * cg;
      }
    }
  }
  const double w = ar / csqrt((double)(2*l3+1));
  return w * 0.10540925533894598;   // fold 1/sqrt(30)/sqrt(3)
}

// ---------------------------------------------------------------------------
// Init kernel (unchanged): repack W_chem (wbody folded) + scrambled nab.
// ---------------------------------------------------------------------------
__global__ void nn3b_init_kernel(const float* __restrict__ node_attr,
                                 const float* __restrict__ W_chem,
                                 const float* __restrict__ wbody,
                                 float* __restrict__ wcB,
                                 float* __restrict__ nab)
{
  const int t = blockIdx.x * 256 + threadIdx.x;

  if (t < WCB_FLOATS){
    const int c = t & 63;
    const int k = (t >> 6) % 30;
    const int d = (t / 1920) % 9;
    const int b = t / 17280;
    wcB[t] = W_chem[k*1728 + d*192 + 3*c + b] * wbody[b];
  }

  const int tc = t - WCB_FLOATS;
  if (tc >= 0 && tc < NAB_FLOATS){
    const int n = tc >> 5;
    const int k = tc & 31;
    float v = 0.0f;
    if (k < 30){
      const int i = 30*n + k;
      v = node_attr[(i % N_NODES)*10 + ((i / N_NODES) % 10)];
    }
    nab[tc] = v;
  }
}

// ---------------------------------------------------------------------------
// R8: producer-consumer fused kernel.
// R7 measured: u staged through HBM cost 276 MB of avoidable traffic and a
// 540 MB workspace poison; R6's fused form was LDS-read-issue-bound (810
// ds_read/thread). This kernel keeps u in LDS and weights in VGPRs:
//   block = 576 threads = 9 waves = the 9 (b, dL-triple) combos.
//   Each wave: 90 weights in VGPRs (loaded once, reused 45 nodes).
//   Per 9-node group: phase 1 = each wave computes its 3 dL of u for all 9
//   nodes -> 27 ds_write; barrier; phase 2 = each wave contracts ONE node
//   (27 ds_read + prefetched v + 249 Wigner-literal FMAs); barrier.
//   v loads are issued before phase 1 so HBM latency hides under 810 FMAs.
// Arithmetic order identical to R7 (u two-chain reduction, EC entry order,
// b order) -> bit-identical output.
// ---------------------------------------------------------------------------
#define LD9(dst, p) { dst[0]=(p)[0]; dst[1]=(p)[1]; dst[2]=(p)[2];        \
                      dst[3]=(p)[3]; dst[4]=(p)[4]; dst[5]=(p)[5];        \
                      dst[6]=(p)[6]; dst[7]=(p)[7]; dst[8]=(p)[8]; }
#define ST9(p, src) { (p)[0]=src[0]; (p)[1]=src[1]; (p)[2]=src[2];        \
                      (p)[3]=src[3]; (p)[4]=src[4]; (p)[5]=src[5];        \
                      (p)[6]=src[6]; (p)[7]=src[7]; (p)[8]=src[8]; }

#define EC(DL,M,S)                                                        \
  {                                                                       \
    constexpr float cc_ = (float)cw_entry(DL,M,S);                        \
    o[S] = fmaf(cc_ * uu[DL], v[M], o[S]);                                \
  }

#define EC_TABLE                                                          \
  EC(0,0,0) EC(0,1,1) EC(0,2,2) EC(0,3,3) EC(0,4,4) EC(0,5,5) EC(0,6,6) EC(0,7,7) EC(0,8,8) \
  EC(1,0,1) EC(1,1,0) EC(1,3,4) EC(1,2,5) EC(1,1,6) EC(1,1,8) EC(1,4,3) EC(1,5,2) EC(1,6,1) EC(1,8,1) \
  EC(2,0,2) EC(2,2,0) EC(2,1,5) EC(2,3,7) EC(2,2,6) EC(2,5,1) EC(2,7,3) EC(2,6,2) \
  EC(3,0,3) EC(3,3,0) EC(3,1,4) EC(3,2,7) EC(3,3,6) EC(3,3,8) EC(3,4,1) EC(3,7,2) EC(3,6,3) EC(3,8,3) \
  EC(4,0,4) EC(4,4,0) EC(4,1,3) EC(4,3,1) EC(4,6,4) EC(4,4,6) EC(4,5,7) EC(4,7,5) \
  EC(5,0,5) EC(5,5,0) EC(5,1,2) EC(5,2,1) EC(5,6,5) EC(5,5,6) EC(5,5,8) EC(5,8,5) EC(5,4,7) EC(5,7,4) \
  EC(6,0,6) EC(6,6,0) EC(6,1,1) EC(6,2,2) EC(6,3,3) EC(6,6,6) EC(6,5,5) EC(6,7,7) EC(6,4,4) EC(6,8,8) \
  EC(7,0,7) EC(7,7,0) EC(7,2,3) EC(7,3,2) EC(7,6,7) EC(7,7,6) EC(7,7,8) EC(7,8,7) EC(7,4,5) EC(7,5,4) \
  EC(8,0,8) EC(8,8,0) EC(8,1,1) EC(8,3,3) EC(8,6,8) EC(8,8,6) EC(8,5,5) EC(8,7,7)

// One body order of phase 2: uu from LDS (literal offsets), v from regs.
#define PHASE2_B(VV, B)                                                   \
  {                                                                       \
    float uu[9];                                                          \
    uu[0]=up[(B)*576+0];   uu[1]=up[(B)*576+64];  uu[2]=up[(B)*576+128];  \
    uu[3]=up[(B)*576+192]; uu[4]=up[(B)*576+256]; uu[5]=up[(B)*576+320];  \
    uu[6]=up[(B)*576+384]; uu[7]=up[(B)*576+448]; uu[8]=up[(B)*576+512];  \
    float v[9];                                                           \
    v[0]=VV[0]; v[1]=VV[1]; v[2]=VV[2]; v[3]=VV[3]; v[4]=VV[4];           \
    v[5]=VV[5]; v[6]=VV[6]; v[7]=VV[7]; v[8]=VV[8];                       \
    EC_TABLE                                                              \
  }

__global__ __launch_bounds__(576)
void nn3b_fused_kernel(const float* __restrict__ nbody,
                       const float* __restrict__ wcB,
                       const float* __restrict__ nab,
                       float* __restrict__ out)
{
  __shared__ __align__(16) float uL[9*27*64];   // 62,208 B: u for one 9-node group

  const int tid = threadIdx.x;
  const int c   = tid & 63;
  const int g   = __builtin_amdgcn_readfirstlane((int)(tid >> 6)); // 0..8
  const int b   = g / 3;          // body order this wave produces
  const int s3  = g - 3*b;        // dL-triple: dL = s3*3 + {0,1,2}
  const int nbase = blockIdx.x * 45;

  // Per-wave weights: 90 VGPRs, reused for all 45 nodes of this block.
  float w0[30], w1[30], w2[30];
  {
    const float* base = wcB + (size_t)((b*9 + s3*3)*30)*64 + c;
    #pragma unroll
    for (int k = 0; k < 30; ++k){
      w0[k] = base[(size_t)k*64];
      w1[k] = base[(size_t)(30+k)*64];
      w2[k] = base[(size_t)(60+k)*64];
    }
  }

  #pragma unroll 1
  for (int grp = 0; grp < 5; ++grp){
    const int n2 = nbase + grp*9 + g;        // my phase-2 node (wave-uniform)

    // v prefetch for phase 2 — issued before the FMA bulk so HBM latency
    // hides under phase 1.
    float v0[9], v1[9], v2[9];
    if (n2 < N_NODES){
      LD9(v0, nbody + ((size_t)(0*N_NODES + n2))*576 + c*9);
      LD9(v1, nbody + ((size_t)(1*N_NODES + n2))*576 + c*9);
      LD9(v2, nbody + ((size_t)(2*N_NODES + n2))*576 + c*9);
    }

    // Phase 1: u[b][dL-triple] for the group's 9 nodes (this wave's combo).
    #pragma unroll 1
    for (int i = 0; i < 9; ++i){
      const int n = nbase + grp*9 + i;       // uniform across block
      if (n >= N_NODES) break;
      const float* na = nab + (size_t)n * 32;
      float a0=0.f, a1=0.f, b0=0.f, b1=0.f, c0=0.f, c1=0.f;
      #pragma unroll
      for (int k = 0; k < 15; ++k){
        const float s0 = na[k];
        const float s1 = na[k+15];
        a0 = fmaf(s0, w0[k],    a0);
        a1 = fmaf(s1, w0[k+15], a1);
        b0 = fmaf(s0, w1[k],    b0);
        b1 = fmaf(s1, w1[k+15], b1);
        c0 = fmaf(s0, w2[k],    c0);
        c1 = fmaf(s1, w2[k+15], c1);
      }
      float* uw = uL + (i*27 + b*9 + s3*3)*64 + c;
      uw[0]   = a0 + a1;
      uw[64]  = b0 + b1;
      uw[128] = c0 + c1;
    }
    __syncthreads();

    // Phase 2: full contraction for node n2 (one node per wave).
    if (n2 < N_NODES){
      float o[9] = {0,0,0,0,0,0,0,0,0};
      const float* up = uL + (g*27)*64 + c;
      PHASE2_B(v0, 0)
      PHASE2_B(v1, 1)
      PHASE2_B(v2, 2)
      ST9(out + (size_t)n2*576 + c*9, o);
    }
    __syncthreads();   // protect uL reuse by next group
  }
}

extern "C" void kernel_launch(void* const* d_in, const int* in_sizes, int n_in,
                              void* d_out, int out_size, void* d_ws, size_t ws_size,
                              hipStream_t stream)
{
  const float* nbody     = (const float*)d_in[0];  // (3, 20000, 64, 9) f32
  const float* node_attr = (const float*)d_in[1];  // (20000, 10) f32
  const float* W_chem    = (const float*)d_in[2];  // (30, 1728) f32
  const float* wbody     = (const float*)d_in[3];  // (3, 1) f32
  float* out = (float*)d_out;                      // (20000, 64, 9) f32

  float* wcB = (float*)d_ws;          // 51840 f
  float* nab = wcB + WCB_FLOATS;      // 640000 f   (total ~2.8 MiB of ws)

  const int init_items  = WCB_FLOATS + NAB_FLOATS;
  const int init_blocks = (init_items + 255) / 256;
  nn3b_init_kernel<<<init_blocks, 256, 0, stream>>>(node_attr, W_chem, wbody, wcB, nab);

  // 445 blocks x 45 nodes = 20025 node slots (last 25 guarded).
  nn3b_fused_kernel<<<445, 576, 0, stream>>>(nbody, wcB, nab, out);
}

// Round 4
// 435.112 us; speedup vs baseline: 1.0264x; 1.0264x over previous
//
#include <hip/hip_runtime.h>

#define N_NODES 20000
#define WCB_FLOATS (3*9*30*64)         // 51840 = repacked W_chem (wbody folded in)
#define NAB_FLOATS (N_NODES*32)        // 30 used per node, padded to 32

// ---------------------------------------------------------------------------
// Compile-time Wigner table (R6, unchanged): identical algorithm to the
// reference, evaluated as constexpr fp64; coefficients inlined as literals.
// ---------------------------------------------------------------------------
struct kx { double re, im; };

__host__ __device__ constexpr kx kmul(kx a, kx b){
  return { a.re*b.re - a.im*b.im, a.re*b.im + a.im*b.re };
}

__host__ __device__ constexpr double cfact(int n){
  double r = 1.0; for (int i = 2; i <= n; ++i) r *= (double)i; return r;
}

__host__ __device__ constexpr double csqrt(double x){
  if (x <= 0.0) return 0.0;
  double g = x > 1.0 ? x : 1.0;
  for (int i = 0; i < 64; ++i) g = 0.5*(g + x/g);   // converged fixed point
  return g;
}

__host__ __device__ constexpr double ccg(int j1,int m1,int j2,int m2,int j3,int m3){
  if (m3 != m1 + m2) return 0.0;
  int vmin = -j1 + j2 + m3;
  if (-j1 + m1 > vmin) vmin = -j1 + m1;
  if (vmin < 0) vmin = 0;
  int vmax = j2 + j3 + m1;
  if (j3 - j1 + j2 < vmax) vmax = j3 - j1 + j2;
  if (j3 + m3 < vmax) vmax = j3 + m3;
  double c = csqrt((double)(2*j3+1) *
      (cfact(j3+j1-j2)*cfact(j3-j1+j2)*cfact(j1+j2-j3)*cfact(j3+m3)*cfact(j3-m3)) /
      (cfact(j1+j2+j3+1)*cfact(j1-m1)*cfact(j1+m1)*cfact(j2-m2)*cfact(j2+m2)));
  double s = 0.0;
  for (int v = vmin; v <= vmax; ++v){
    double t = (cfact(j2+j3+m1-v)*cfact(j1-m1+v)) /
               (cfact(v)*cfact(j3-j1+j2-v)*cfact(j3+m3-v)*cfact(v+j1-j2-m3));
    s += ((v + j2 + m2) & 1) ? -t : t;
  }
  return c * s;
}

__host__ __device__ constexpr kx cq(int l, int r, int c){
  kx v = {0.0, 0.0};
  const double is2 = 0.70710678118654752440;
  const int m = r - l;
  if (m < 0){
    if (c == 2*l - r)      v = { is2, 0.0 };
    else if (c == r)       v = { 0.0, -is2 };
  } else if (m == 0){
    if (c == l)            v = { 1.0, 0.0 };
  } else {
    const double sg = (m & 1) ? -1.0 : 1.0;
    if (c == r)            v = { sg*is2, 0.0 };
    else if (c == 2*l - r) v = { 0.0, sg*is2 };
  }
  if (l == 1)      v = { v.im, -v.re };   // * (-i)
  else if (l == 2) v = { -v.re, -v.im };  // * (-i)^2 = -1
  return v;
}

__host__ __device__ constexpr double cw_entry(int L, int M, int S){
  const int l1 = (L==0)?0:((L<4)?1:2);
  const int l2 = (M==0)?0:((M<4)?1:2);
  const int l3 = (S==0)?0:((S<4)?1:2);
  const int a  = L - ((l1==0)?0:((l1==1)?1:4));
  const int b  = M - ((l2==0)?0:((l2==1)?1:4));
  const int cc = S - ((l3==0)?0:((l3==1)?1:4));
  const int lo = (l1 > l2) ? l1 - l2 : l2 - l1;
  if (!(l3 >= lo && l3 <= l1 + l2 && (((l1 + l2 + l3) & 1) == 0))) return 0.0;
  double ar = 0.0, ai = 0.0;
  for (int i = 0; i < 2*l1+1; ++i){
    kx q1 = cq(l1, i, a);
    if (q1.re == 0.0 && q1.im == 0.0) continue;
    for (int k = 0; k < 2*l2+1; ++k){
      kx q2 = cq(l2, k, b);
      if (q2.re == 0.0 && q2.im == 0.0) continue;
      kx q12 = kmul(q1, q2);
      for (int n = 0; n < 2*l3+1; ++n){
        kx q3 = cq(l3, n, cc);
        if (q3.re == 0.0 && q3.im == 0.0) continue;
        double cg = ccg(l1, i-l1, l2, k-l2, l3, n-l3);
        if (cg == 0.0) continue;
        kx q3c = { q3.re, -q3.im };
        kx term = kmul(q12, q3c);
        ar += term.re * cg;
        ai += term.im * cg;
      }
    }
  }
  const double w = ar / csqrt((double)(2*l3+1));
  return w * 0.10540925533894598;   // fold 1/sqrt(30)/sqrt(3)
}

// ---------------------------------------------------------------------------
// Init kernel (unchanged): repack W_chem (wbody folded) + scrambled nab.
// ---------------------------------------------------------------------------
__global__ void nn3b_init_kernel(const float* __restrict__ node_attr,
                                 const float* __restrict__ W_chem,
                                 const float* __restrict__ wbody,
                                 float* __restrict__ wcB,
                                 float* __restrict__ nab)
{
  const int t = blockIdx.x * 256 + threadIdx.x;

  if (t < WCB_FLOATS){
    const int c = t & 63;
    const int k = (t >> 6) % 30;
    const int d = (t / 1920) % 9;
    const int b = t / 17280;
    wcB[t] = W_chem[k*1728 + d*192 + 3*c + b] * wbody[b];
  }

  const int tc = t - WCB_FLOATS;
  if (tc >= 0 && tc < NAB_FLOATS){
    const int n = tc >> 5;
    const int k = tc & 31;
    float v = 0.0f;
    if (k < 30){
      const int i = 30*n + k;
      v = node_attr[(i % N_NODES)*10 + ((i / N_NODES) % 10)];
    }
    nab[tc] = v;
  }
}

// ---------------------------------------------------------------------------
// R9: producer-consumer fused kernel, register-budget-fixed.
// R8 post-mortem: hipcc's occupancy heuristic (default ~6 waves/EU for a
// 576-thread block) capped VGPR at 84 and spilled the 90-weight + 27-v
// register state to scratch -> ~750 MB of scratch HBM traffic (FETCH 363 MB,
// WRITE 571 MB) and 300 us at VALUBusy 15%.
// Fix 1: __launch_bounds__(576, 3) -> min 3 waves/EU -> VGPR budget 170,
//        which holds the ~150 live regs with zero spill (1 block/CU).
// Fix 2: 27 nodes/block (3 groups) -> 741 blocks: ~2.9 scheduling rounds at
//        1 block/CU (<=4% tail loss vs 13% at 445 blocks).
// Structure and arithmetic order identical to R8 -> bit-identical output.
// ---------------------------------------------------------------------------
#define LD9(dst, p) { dst[0]=(p)[0]; dst[1]=(p)[1]; dst[2]=(p)[2];        \
                      dst[3]=(p)[3]; dst[4]=(p)[4]; dst[5]=(p)[5];        \
                      dst[6]=(p)[6]; dst[7]=(p)[7]; dst[8]=(p)[8]; }
#define ST9(p, src) { (p)[0]=src[0]; (p)[1]=src[1]; (p)[2]=src[2];        \
                      (p)[3]=src[3]; (p)[4]=src[4]; (p)[5]=src[5];        \
                      (p)[6]=src[6]; (p)[7]=src[7]; (p)[8]=src[8]; }

#define EC(DL,M,S)                                                        \
  {                                                                       \
    constexpr float cc_ = (float)cw_entry(DL,M,S);                        \
    o[S] = fmaf(cc_ * uu[DL], v[M], o[S]);                                \
  }

#define EC_TABLE                                                          \
  EC(0,0,0) EC(0,1,1) EC(0,2,2) EC(0,3,3) EC(0,4,4) EC(0,5,5) EC(0,6,6) EC(0,7,7) EC(0,8,8) \
  EC(1,0,1) EC(1,1,0) EC(1,3,4) EC(1,2,5) EC(1,1,6) EC(1,1,8) EC(1,4,3) EC(1,5,2) EC(1,6,1) EC(1,8,1) \
  EC(2,0,2) EC(2,2,0) EC(2,1,5) EC(2,3,7) EC(2,2,6) EC(2,5,1) EC(2,7,3) EC(2,6,2) \
  EC(3,0,3) EC(3,3,0) EC(3,1,4) EC(3,2,7) EC(3,3,6) EC(3,3,8) EC(3,4,1) EC(3,7,2) EC(3,6,3) EC(3,8,3) \
  EC(4,0,4) EC(4,4,0) EC(4,1,3) EC(4,3,1) EC(4,6,4) EC(4,4,6) EC(4,5,7) EC(4,7,5) \
  EC(5,0,5) EC(5,5,0) EC(5,1,2) EC(5,2,1) EC(5,6,5) EC(5,5,6) EC(5,5,8) EC(5,8,5) EC(5,4,7) EC(5,7,4) \
  EC(6,0,6) EC(6,6,0) EC(6,1,1) EC(6,2,2) EC(6,3,3) EC(6,6,6) EC(6,5,5) EC(6,7,7) EC(6,4,4) EC(6,8,8) \
  EC(7,0,7) EC(7,7,0) EC(7,2,3) EC(7,3,2) EC(7,6,7) EC(7,7,6) EC(7,7,8) EC(7,8,7) EC(7,4,5) EC(7,5,4) \
  EC(8,0,8) EC(8,8,0) EC(8,1,1) EC(8,3,3) EC(8,6,8) EC(8,8,6) EC(8,5,5) EC(8,7,7)

// One body order of phase 2: uu from LDS (literal offsets), v from regs.
#define PHASE2_B(VV, B)                                                   \
  {                                                                       \
    float uu[9];                                                          \
    uu[0]=up[(B)*576+0];   uu[1]=up[(B)*576+64];  uu[2]=up[(B)*576+128];  \
    uu[3]=up[(B)*576+192]; uu[4]=up[(B)*576+256]; uu[5]=up[(B)*576+320];  \
    uu[6]=up[(B)*576+384]; uu[7]=up[(B)*576+448]; uu[8]=up[(B)*576+512];  \
    float v[9];                                                           \
    v[0]=VV[0]; v[1]=VV[1]; v[2]=VV[2]; v[3]=VV[3]; v[4]=VV[4];           \
    v[5]=VV[5]; v[6]=VV[6]; v[7]=VV[7]; v[8]=VV[8];                       \
    EC_TABLE                                                              \
  }

__global__ __launch_bounds__(576, 3)   // 3 waves/EU min -> VGPR budget ~170
void nn3b_fused_kernel(const float* __restrict__ nbody,
                       const float* __restrict__ wcB,
                       const float* __restrict__ nab,
                       float* __restrict__ out)
{
  __shared__ __align__(16) float uL[9*27*64];   // 62,208 B: u for one 9-node group

  const int tid = threadIdx.x;
  const int c   = tid & 63;
  const int g   = __builtin_amdgcn_readfirstlane((int)(tid >> 6)); // 0..8
  const int b   = g / 3;          // body order this wave produces
  const int s3  = g - 3*b;        // dL-triple: dL = s3*3 + {0,1,2}
  const int nbase = blockIdx.x * 27;

  // Per-wave weights: 90 VGPRs, reused for all 27 nodes of this block.
  float w0[30], w1[30], w2[30];
  {
    const float* base = wcB + (size_t)((b*9 + s3*3)*30)*64 + c;
    #pragma unroll
    for (int k = 0; k < 30; ++k){
      w0[k] = base[(size_t)k*64];
      w1[k] = base[(size_t)(30+k)*64];
      w2[k] = base[(size_t)(60+k)*64];
    }
  }

  #pragma unroll 1
  for (int grp = 0; grp < 3; ++grp){
    const int n2 = nbase + grp*9 + g;        // my phase-2 node (wave-uniform)

    // v prefetch for phase 2 — issued before the FMA bulk so HBM latency
    // hides under phase 1's 810 FMAs.
    float v0[9], v1[9], v2[9];
    if (n2 < N_NODES){
      LD9(v0, nbody + ((size_t)(0*N_NODES + n2))*576 + c*9);
      LD9(v1, nbody + ((size_t)(1*N_NODES + n2))*576 + c*9);
      LD9(v2, nbody + ((size_t)(2*N_NODES + n2))*576 + c*9);
    }

    // Phase 1: u[b][dL-triple] for the group's 9 nodes (this wave's combo).
    #pragma unroll 1
    for (int i = 0; i < 9; ++i){
      const int n = nbase + grp*9 + i;       // uniform across block
      if (n >= N_NODES) break;
      const float* na = nab + (size_t)n * 32;
      float a0=0.f, a1=0.f, b0=0.f, b1=0.f, c0=0.f, c1=0.f;
      #pragma unroll
      for (int k = 0; k < 15; ++k){
        const float s0 = na[k];
        const float s1 = na[k+15];
        a0 = fmaf(s0, w0[k],    a0);
        a1 = fmaf(s1, w0[k+15], a1);
        b0 = fmaf(s0, w1[k],    b0);
        b1 = fmaf(s1, w1[k+15], b1);
        c0 = fmaf(s0, w2[k],    c0);
        c1 = fmaf(s1, w2[k+15], c1);
      }
      float* uw = uL + (i*27 + b*9 + s3*3)*64 + c;
      uw[0]   = a0 + a1;
      uw[64]  = b0 + b1;
      uw[128] = c0 + c1;
    }
    __syncthreads();

    // Phase 2: full contraction for node n2 (one node per wave).
    if (n2 < N_NODES){
      float o[9] = {0,0,0,0,0,0,0,0,0};
      const float* up = uL + (g*27)*64 + c;
      PHASE2_B(v0, 0)
      PHASE2_B(v1, 1)
      PHASE2_B(v2, 2)
      ST9(out + (size_t)n2*576 + c*9, o);
    }
    __syncthreads();   // protect uL reuse by next group
  }
}

extern "C" void kernel_launch(void* const* d_in, const int* in_sizes, int n_in,
                              void* d_out, int out_size, void* d_ws, size_t ws_size,
                              hipStream_t stream)
{
  const float* nbody     = (const float*)d_in[0];  // (3, 20000, 64, 9) f32
  const float* node_attr = (const float*)d_in[1];  // (20000, 10) f32
  const float* W_chem    = (const float*)d_in[2];  // (30, 1728) f32
  const float* wbody     = (const float*)d_in[3];  // (3, 1) f32
  float* out = (float*)d_out;                      // (20000, 64, 9) f32

  float* wcB = (float*)d_ws;          // 51840 f
  float* nab = wcB + WCB_FLOATS;      // 640000 f   (total ~2.8 MiB of ws)

  const int init_items  = WCB_FLOATS + NAB_FLOATS;
  const int init_blocks = (init_items + 255) / 256;
  nn3b_init_kernel<<<init_blocks, 256, 0, stream>>>(node_attr, W_chem, wbody, wcB, nab);

  // 741 blocks x 27 nodes = 20007 node slots (last 7 guarded).
  nn3b_fused_kernel<<<741, 576, 0, stream>>>(nbody, wcB, nab, out);
}

// Round 5
// 425.261 us; speedup vs baseline: 1.0502x; 1.0232x over previous
//
#include <hip/hip_runtime.h>

#define N_NODES 20000
#define WCB_FLOATS (3*9*30*64)         // 51840 = repacked W_chem (wbody folded in)
#define NAB_FLOATS (N_NODES*32)        // 30 used per node, padded to 32

// ---------------------------------------------------------------------------
// Compile-time Wigner table (R6, unchanged): identical algorithm to the
// reference, evaluated as constexpr fp64; coefficients inlined as literals.
// ---------------------------------------------------------------------------
struct kx { double re, im; };

__host__ __device__ constexpr kx kmul(kx a, kx b){
  return { a.re*b.re - a.im*b.im, a.re*b.im + a.im*b.re };
}

__host__ __device__ constexpr double cfact(int n){
  double r = 1.0; for (int i = 2; i <= n; ++i) r *= (double)i; return r;
}

__host__ __device__ constexpr double csqrt(double x){
  if (x <= 0.0) return 0.0;
  double g = x > 1.0 ? x : 1.0;
  for (int i = 0; i < 64; ++i) g = 0.5*(g + x/g);   // converged fixed point
  return g;
}

__host__ __device__ constexpr double ccg(int j1,int m1,int j2,int m2,int j3,int m3){
  if (m3 != m1 + m2) return 0.0;
  int vmin = -j1 + j2 + m3;
  if (-j1 + m1 > vmin) vmin = -j1 + m1;
  if (vmin < 0) vmin = 0;
  int vmax = j2 + j3 + m1;
  if (j3 - j1 + j2 < vmax) vmax = j3 - j1 + j2;
  if (j3 + m3 < vmax) vmax = j3 + m3;
  double c = csqrt((double)(2*j3+1) *
      (cfact(j3+j1-j2)*cfact(j3-j1+j2)*cfact(j1+j2-j3)*cfact(j3+m3)*cfact(j3-m3)) /
      (cfact(j1+j2+j3+1)*cfact(j1-m1)*cfact(j1+m1)*cfact(j2-m2)*cfact(j2+m2)));
  double s = 0.0;
  for (int v = vmin; v <= vmax; ++v){
    double t = (cfact(j2+j3+m1-v)*cfact(j1-m1+v)) /
               (cfact(v)*cfact(j3-j1+j2-v)*cfact(j3+m3-v)*cfact(v+j1-j2-m3));
    s += ((v + j2 + m2) & 1) ? -t : t;
  }
  return c * s;
}

__host__ __device__ constexpr kx cq(int l, int r, int c){
  kx v = {0.0, 0.0};
  const double is2 = 0.70710678118654752440;
  const int m = r - l;
  if (m < 0){
    if (c == 2*l - r)      v = { is2, 0.0 };
    else if (c == r)       v = { 0.0, -is2 };
  } else if (m == 0){
    if (c == l)            v = { 1.0, 0.0 };
  } else {
    const double sg = (m & 1) ? -1.0 : 1.0;
    if (c == r)            v = { sg*is2, 0.0 };
    else if (c == 2*l - r) v = { 0.0, sg*is2 };
  }
  if (l == 1)      v = { v.im, -v.re };   // * (-i)
  else if (l == 2) v = { -v.re, -v.im };  // * (-i)^2 = -1
  return v;
}

__host__ __device__ constexpr double cw_entry(int L, int M, int S){
  const int l1 = (L==0)?0:((L<4)?1:2);
  const int l2 = (M==0)?0:((M<4)?1:2);
  const int l3 = (S==0)?0:((S<4)?1:2);
  const int a  = L - ((l1==0)?0:((l1==1)?1:4));
  const int b  = M - ((l2==0)?0:((l2==1)?1:4));
  const int cc = S - ((l3==0)?0:((l3==1)?1:4));
  const int lo = (l1 > l2) ? l1 - l2 : l2 - l1;
  if (!(l3 >= lo && l3 <= l1 + l2 && (((l1 + l2 + l3) & 1) == 0))) return 0.0;
  double ar = 0.0, ai = 0.0;
  for (int i = 0; i < 2*l1+1; ++i){
    kx q1 = cq(l1, i, a);
    if (q1.re == 0.0 && q1.im == 0.0) continue;
    for (int k = 0; k < 2*l2+1; ++k){
      kx q2 = cq(l2, k, b);
      if (q2.re == 0.0 && q2.im == 0.0) continue;
      kx q12 = kmul(q1, q2);
      for (int n = 0; n < 2*l3+1; ++n){
        kx q3 = cq(l3, n, cc);
        if (q3.re == 0.0 && q3.im == 0.0) continue;
        double cg = ccg(l1, i-l1, l2, k-l2, l3, n-l3);
        if (cg == 0.0) continue;
        kx q3c = { q3.re, -q3.im };
        kx term = kmul(q12, q3c);
        ar += term.re * cg;
        ai += term.im * cg;
      }
    }
  }
  const double w = ar / csqrt((double)(2*l3+1));
  return w * 0.10540925533894598;   // fold 1/sqrt(30)/sqrt(3)
}

// ---------------------------------------------------------------------------
// Init kernel (unchanged): repack W_chem (wbody folded) + scrambled nab.
// ---------------------------------------------------------------------------
__global__ void nn3b_init_kernel(const float* __restrict__ node_attr,
                                 const float* __restrict__ W_chem,
                                 const float* __restrict__ wbody,
                                 float* __restrict__ wcB,
                                 float* __restrict__ nab)
{
  const int t = blockIdx.x * 256 + threadIdx.x;

  if (t < WCB_FLOATS){
    const int c = t & 63;
    const int k = (t >> 6) % 30;
    const int d = (t / 1920) % 9;
    const int b = t / 17280;
    wcB[t] = W_chem[k*1728 + d*192 + 3*c + b] * wbody[b];
  }

  const int tc = t - WCB_FLOATS;
  if (tc >= 0 && tc < NAB_FLOATS){
    const int n = tc >> 5;
    const int k = tc & 31;
    float v = 0.0f;
    if (k < 30){
      const int i = 30*n + k;
      v = node_attr[(i % N_NODES)*10 + ((i / N_NODES) % 10)];
    }
    nab[tc] = v;
  }
}

// ---------------------------------------------------------------------------
// R10: producer-consumer fused kernel, occupancy target pinned.
// R9 post-mortem: __launch_bounds__(576, 3) left VGPR_Count at 84 — the
// second arg only sets a LOWER bound on waves/EU, which the default 6-wave
// heuristic already satisfied, so the allocator still capped at 512/6=84 and
// spilled ~790 MB of scratch (FETCH 367 MB / WRITE 605 MB, VALUBusy 15%).
// Fix: __attribute__((amdgpu_waves_per_eu(3, 3))) pins the backend's
// occupancy target to exactly 3 waves/EU -> VGPR budget ~170, which holds
// the ~140 live regs (90 weights + 27 v-prefetch + accs) with zero spill.
// 9-wave blocks remain legal (<=3 waves on any one SIMD at 170 VGPR).
// Structure and arithmetic order identical to R8/R9 -> bit-identical output.
// PASS/FAIL signal for this round: VGPR_Count ~150-168 and WRITE_SIZE ~45 MB.
// ---------------------------------------------------------------------------
#define LD9(dst, p) { dst[0]=(p)[0]; dst[1]=(p)[1]; dst[2]=(p)[2];        \
                      dst[3]=(p)[3]; dst[4]=(p)[4]; dst[5]=(p)[5];        \
                      dst[6]=(p)[6]; dst[7]=(p)[7]; dst[8]=(p)[8]; }
#define ST9(p, src) { (p)[0]=src[0]; (p)[1]=src[1]; (p)[2]=src[2];        \
                      (p)[3]=src[3]; (p)[4]=src[4]; (p)[5]=src[5];        \
                      (p)[6]=src[6]; (p)[7]=src[7]; (p)[8]=src[8]; }

#define EC(DL,M,S)                                                        \
  {                                                                       \
    constexpr float cc_ = (float)cw_entry(DL,M,S);                        \
    o[S] = fmaf(cc_ * uu[DL], v[M], o[S]);                                \
  }

#define EC_TABLE                                                          \
  EC(0,0,0) EC(0,1,1) EC(0,2,2) EC(0,3,3) EC(0,4,4) EC(0,5,5) EC(0,6,6) EC(0,7,7) EC(0,8,8) \
  EC(1,0,1) EC(1,1,0) EC(1,3,4) EC(1,2,5) EC(1,1,6) EC(1,1,8) EC(1,4,3) EC(1,5,2) EC(1,6,1) EC(1,8,1) \
  EC(2,0,2) EC(2,2,0) EC(2,1,5) EC(2,3,7) EC(2,2,6) EC(2,5,1) EC(2,7,3) EC(2,6,2) \
  EC(3,0,3) EC(3,3,0) EC(3,1,4) EC(3,2,7) EC(3,3,6) EC(3,3,8) EC(3,4,1) EC(3,7,2) EC(3,6,3) EC(3,8,3) \
  EC(4,0,4) EC(4,4,0) EC(4,1,3) EC(4,3,1) EC(4,6,4) EC(4,4,6) EC(4,5,7) EC(4,7,5) \
  EC(5,0,5) EC(5,5,0) EC(5,1,2) EC(5,2,1) EC(5,6,5) EC(5,5,6) EC(5,5,8) EC(5,8,5) EC(5,4,7) EC(5,7,4) \
  EC(6,0,6) EC(6,6,0) EC(6,1,1) EC(6,2,2) EC(6,3,3) EC(6,6,6) EC(6,5,5) EC(6,7,7) EC(6,4,4) EC(6,8,8) \
  EC(7,0,7) EC(7,7,0) EC(7,2,3) EC(7,3,2) EC(7,6,7) EC(7,7,6) EC(7,7,8) EC(7,8,7) EC(7,4,5) EC(7,5,4) \
  EC(8,0,8) EC(8,8,0) EC(8,1,1) EC(8,3,3) EC(8,6,8) EC(8,8,6) EC(8,5,5) EC(8,7,7)

// One body order of phase 2: uu from LDS (literal offsets), v from regs.
#define PHASE2_B(VV, B)                                                   \
  {                                                                       \
    float uu[9];                                                          \
    uu[0]=up[(B)*576+0];   uu[1]=up[(B)*576+64];  uu[2]=up[(B)*576+128];  \
    uu[3]=up[(B)*576+192]; uu[4]=up[(B)*576+256]; uu[5]=up[(B)*576+320];  \
    uu[6]=up[(B)*576+384]; uu[7]=up[(B)*576+448]; uu[8]=up[(B)*576+512];  \
    float v[9];                                                           \
    v[0]=VV[0]; v[1]=VV[1]; v[2]=VV[2]; v[3]=VV[3]; v[4]=VV[4];           \
    v[5]=VV[5]; v[6]=VV[6]; v[7]=VV[7]; v[8]=VV[8];                       \
    EC_TABLE                                                              \
  }

__global__ __launch_bounds__(576)
__attribute__((amdgpu_waves_per_eu(3, 3)))   // pin target: VGPR budget ~170
void nn3b_fused_kernel(const float* __restrict__ nbody,
                       const float* __restrict__ wcB,
                       const float* __restrict__ nab,
                       float* __restrict__ out)
{
  __shared__ __align__(16) float uL[9*27*64];   // 62,208 B: u for one 9-node group

  const int tid = threadIdx.x;
  const int c   = tid & 63;
  const int g   = __builtin_amdgcn_readfirstlane((int)(tid >> 6)); // 0..8
  const int b   = g / 3;          // body order this wave produces
  const int s3  = g - 3*b;        // dL-triple: dL = s3*3 + {0,1,2}
  const int nbase = blockIdx.x * 27;

  // Per-wave weights: 90 VGPRs, reused for all 27 nodes of this block.
  float w0[30], w1[30], w2[30];
  {
    const float* base = wcB + (size_t)((b*9 + s3*3)*30)*64 + c;
    #pragma unroll
    for (int k = 0; k < 30; ++k){
      w0[k] = base[(size_t)k*64];
      w1[k] = base[(size_t)(30+k)*64];
      w2[k] = base[(size_t)(60+k)*64];
    }
  }

  #pragma unroll 1
  for (int grp = 0; grp < 3; ++grp){
    const int n2 = nbase + grp*9 + g;        // my phase-2 node (wave-uniform)

    // v prefetch for phase 2 — issued before the FMA bulk so HBM latency
    // hides under phase 1's 810 FMAs.
    float v0[9], v1[9], v2[9];
    if (n2 < N_NODES){
      LD9(v0, nbody + ((size_t)(0*N_NODES + n2))*576 + c*9);
      LD9(v1, nbody + ((size_t)(1*N_NODES + n2))*576 + c*9);
      LD9(v2, nbody + ((size_t)(2*N_NODES + n2))*576 + c*9);
    }

    // Phase 1: u[b][dL-triple] for the group's 9 nodes (this wave's combo).
    #pragma unroll 1
    for (int i = 0; i < 9; ++i){
      const int n = nbase + grp*9 + i;       // uniform across block
      if (n >= N_NODES) break;
      const float* na = nab + (size_t)n * 32;
      float a0=0.f, a1=0.f, b0=0.f, b1=0.f, c0=0.f, c1=0.f;
      #pragma unroll
      for (int k = 0; k < 15; ++k){
        const float s0 = na[k];
        const float s1 = na[k+15];
        a0 = fmaf(s0, w0[k],    a0);
        a1 = fmaf(s1, w0[k+15], a1);
        b0 = fmaf(s0, w1[k],    b0);
        b1 = fmaf(s1, w1[k+15], b1);
        c0 = fmaf(s0, w2[k],    c0);
        c1 = fmaf(s1, w2[k+15], c1);
      }
      float* uw = uL + (i*27 + b*9 + s3*3)*64 + c;
      uw[0]   = a0 + a1;
      uw[64]  = b0 + b1;
      uw[128] = c0 + c1;
    }
    __syncthreads();

    // Phase 2: full contraction for node n2 (one node per wave).
    if (n2 < N_NODES){
      float o[9] = {0,0,0,0,0,0,0,0,0};
      const float* up = uL + (g*27)*64 + c;
      PHASE2_B(v0, 0)
      PHASE2_B(v1, 1)
      PHASE2_B(v2, 2)
      ST9(out + (size_t)n2*576 + c*9, o);
    }
    __syncthreads();   // protect uL reuse by next group
  }
}

extern "C" void kernel_launch(void* const* d_in, const int* in_sizes, int n_in,
                              void* d_out, int out_size, void* d_ws, size_t ws_size,
                              hipStream_t stream)
{
  const float* nbody     = (const float*)d_in[0];  // (3, 20000, 64, 9) f32
  const float* node_attr = (const float*)d_in[1];  // (20000, 10) f32
  const float* W_chem    = (const float*)d_in[2];  // (30, 1728) f32
  const float* wbody     = (const float*)d_in[3];  // (3, 1) f32
  float* out = (float*)d_out;                      // (20000, 64, 9) f32

  float* wcB = (float*)d_ws;          // 51840 f
  float* nab = wcB + WCB_FLOATS;      // 640000 f   (total ~2.8 MiB of ws)

  const int init_items  = WCB_FLOATS + NAB_FLOATS;
  const int init_blocks = (init_items + 255) / 256;
  nn3b_init_kernel<<<init_blocks, 256, 0, stream>>>(node_attr, W_chem, wbody, wcB, nab);

  // 741 blocks x 27 nodes = 20007 node slots (last 7 guarded).
  nn3b_fused_kernel<<<741, 576, 0, stream>>>(nbody, wcB, nab, out);
}

// Round 9
// 329.696 us; speedup vs baseline: 1.3546x; 1.2899x over previous
//
#include <hip/hip_runtime.h>

#define N_NODES 20000
#define WCB_FLOATS (3*9*30*64)         // 51840 = repacked W_chem (wbody folded in)
#define NAB_FLOATS (N_NODES*32)        // 30 used per node, padded to 32

// ---------------------------------------------------------------------------
// Compile-time Wigner table (R6, unchanged): identical algorithm to the
// reference, evaluated as constexpr fp64; coefficients inlined as literals.
// ---------------------------------------------------------------------------
struct kx { double re, im; };

__host__ __device__ constexpr kx kmul(kx a, kx b){
  return { a.re*b.re - a.im*b.im, a.re*b.im + a.im*b.re };
}

__host__ __device__ constexpr double cfact(int n){
  double r = 1.0; for (int i = 2; i <= n; ++i) r *= (double)i; return r;
}

__host__ __device__ constexpr double csqrt(double x){
  if (x <= 0.0) return 0.0;
  double g = x > 1.0 ? x : 1.0;
  for (int i = 0; i < 64; ++i) g = 0.5*(g + x/g);   // converged fixed point
  return g;
}

__host__ __device__ constexpr double ccg(int j1,int m1,int j2,int m2,int j3,int m3){
  if (m3 != m1 + m2) return 0.0;
  int vmin = -j1 + j2 + m3;
  if (-j1 + m1 > vmin) vmin = -j1 + m1;
  if (vmin < 0) vmin = 0;
  int vmax = j2 + j3 + m1;
  if (j3 - j1 + j2 < vmax) vmax = j3 - j1 + j2;
  if (j3 + m3 < vmax) vmax = j3 + m3;
  double c = csqrt((double)(2*j3+1) *
      (cfact(j3+j1-j2)*cfact(j3-j1+j2)*cfact(j1+j2-j3)*cfact(j3+m3)*cfact(j3-m3)) /
      (cfact(j1+j2+j3+1)*cfact(j1-m1)*cfact(j1+m1)*cfact(j2-m2)*cfact(j2+m2)));
  double s = 0.0;
  for (int v = vmin; v <= vmax; ++v){
    double t = (cfact(j2+j3+m1-v)*cfact(j1-m1+v)) /
               (cfact(v)*cfact(j3-j1+j2-v)*cfact(j3+m3-v)*cfact(v+j1-j2-m3));
    s += ((v + j2 + m2) & 1) ? -t : t;
  }
  return c * s;
}

__host__ __device__ constexpr kx cq(int l, int r, int c){
  kx v = {0.0, 0.0};
  const double is2 = 0.70710678118654752440;
  const int m = r - l;
  if (m < 0){
    if (c == 2*l - r)      v = { is2, 0.0 };
    else if (c == r)       v = { 0.0, -is2 };
  } else if (m == 0){
    if (c == l)            v = { 1.0, 0.0 };
  } else {
    const double sg = (m & 1) ? -1.0 : 1.0;
    if (c == r)            v = { sg*is2, 0.0 };
    else if (c == 2*l - r) v = { 0.0, sg*is2 };
  }
  if (l == 1)      v = { v.im, -v.re };   // * (-i)
  else if (l == 2) v = { -v.re, -v.im };  // * (-i)^2 = -1
  return v;
}

__host__ __device__ constexpr double cw_entry(int L, int M, int S){
  const int l1 = (L==0)?0:((L<4)?1:2);
  const int l2 = (M==0)?0:((M<4)?1:2);
  const int l3 = (S==0)?0:((S<4)?1:2);
  const int a  = L - ((l1==0)?0:((l1==1)?1:4));
  const int b  = M - ((l2==0)?0:((l2==1)?1:4));
  const int cc = S - ((l3==0)?0:((l3==1)?1:4));
  const int lo = (l1 > l2) ? l1 - l2 : l2 - l1;
  if (!(l3 >= lo && l3 <= l1 + l2 && (((l1 + l2 + l3) & 1) == 0))) return 0.0;
  double ar = 0.0, ai = 0.0;
  for (int i = 0; i < 2*l1+1; ++i){
    kx q1 = cq(l1, i, a);
    if (q1.re == 0.0 && q1.im == 0.0) continue;
    for (int k = 0; k < 2*l2+1; ++k){
      kx q2 = cq(l2, k, b);
      if (q2.re == 0.0 && q2.im == 0.0) continue;
      kx q12 = kmul(q1, q2);
      for (int n = 0; n < 2*l3+1; ++n){
        kx q3 = cq(l3, n, cc);
        if (q3.re == 0.0 && q3.im == 0.0) continue;
        double cg = ccg(l1, i-l1, l2, k-l2, l3, n-l3);
        if (cg == 0.0) continue;
        kx q3c = { q3.re, -q3.im };
        kx term = kmul(q12, q3c);
        ar += term.re * cg;
        ai += term.im * cg;
      }
    }
  }
  const double w = ar / csqrt((double)(2*l3+1));
  return w * 0.10540925533894598;   // fold 1/sqrt(30)/sqrt(3)
}

// ---------------------------------------------------------------------------
// Init kernel: EXACTLY the R6 version (known to run on this harness).
// Job B: repack W_chem -> wcB[b][d][k][c] = W_chem[k, d*192+3c+b] * wbody[b]
// Job C: scrambled chem rows, padded to 32 floats/node for scalar loads
// ---------------------------------------------------------------------------
__global__ void nn3b_init_kernel(const float* __restrict__ node_attr,
                                 const float* __restrict__ W_chem,
                                 const float* __restrict__ wbody,
                                 float* __restrict__ wcB,
                                 float* __restrict__ nab)
{
  const int t = blockIdx.x * 256 + threadIdx.x;

  if (t < WCB_FLOATS){
    const int c = t & 63;
    const int k = (t >> 6) % 30;
    const int d = (t / 1920) % 9;
    const int b = t / 17280;
    wcB[t] = W_chem[k*1728 + d*192 + 3*c + b] * wbody[b];
  }

  const int tc = t - WCB_FLOATS;
  if (tc >= 0 && tc < NAB_FLOATS){
    const int n = tc >> 5;
    const int k = tc & 31;
    float v = 0.0f;
    if (k < 30){
      const int i = 30*n + k;
      v = node_attr[(i % N_NODES)*10 + ((i / N_NODES) % 10)];
    }
    nab[tc] = v;
  }
}

// ---------------------------------------------------------------------------
// R14 main kernel: bisection step after 3x container failure of the R11
// source (R0-R5 and R6's structures all ran; R11's novelties were float4 LDS
// reads + quad-packed weights). This kernel keeps ONLY the NP=4 change on
// top of the verbatim R6 structure: same init/wcB layout, same STAGE, same
// scalar ds_read_b32 UCOMP shape — but each thread serves 4 nodes, halving
// chip-wide LDS instruction count (R6's measured bottleneck).
// Theory: R6 was LDS-issue-bound (810 ds_read_b32/thread, 2 nodes).
// NP=4: same 810 reads serve 4 nodes; total threads halve -> LDS issue
// ~76 -> ~38 us; VALU ~unchanged chip-wide; HBM 183 MB ~30 us.
// Live regs ~105 (o 36 + v 36 + accs) -> inside proven 124-reg budget.
// Arithmetic order identical to R6 -> bit-identical output.
// ---------------------------------------------------------------------------
#define LD9(dst, p) { dst[0]=(p)[0]; dst[1]=(p)[1]; dst[2]=(p)[2];        \
                      dst[3]=(p)[3]; dst[4]=(p)[4]; dst[5]=(p)[5];        \
                      dst[6]=(p)[6]; dst[7]=(p)[7]; dst[8]=(p)[8]; }
#define ST9(p, src) { (p)[0]=src[0]; (p)[1]=src[1]; (p)[2]=src[2];        \
                      (p)[3]=src[3]; (p)[4]=src[4]; (p)[5]=src[5];        \
                      (p)[6]=src[6]; (p)[7]=src[7]; (p)[8]=src[8]; }

// Stage chunk Q (3 dL slabs = 5760 floats = 1440 float4) of wcb_b into LDS.
// Verbatim R6 STAGE (ran at 150 us / 269 us bench).
#define STAGE(Q)                                                          \
  __syncthreads();                                                        \
  {                                                                       \
    const float4* src4 = (const float4*)(wcb_b + (Q)*5760);               \
    float4* dst4 = (float4*)ldsw;                                         \
    dst4[tid]       = src4[tid];                                          \
    dst4[tid + 512] = src4[tid + 512];                                    \
    if (tid < 416) dst4[tid + 1024] = src4[tid + 1024];                   \
  }                                                                       \
  __syncthreads();

// u for one dL from LDS slab SLAB (0..2): R6's two-half-chain order,
// extended from 2 to 4 nodes. Same w0/w1 scalar ds_read_b32 pattern.
#define UCOMP4(SLAB)                                                      \
  {                                                                       \
    float a0=0.f,a1=0.f, b0=0.f,b1=0.f, c0=0.f,c1=0.f, d0=0.f,d1=0.f;     \
    const float* wp = ldsw + (SLAB)*1920 + c;                             \
    _Pragma("unroll")                                                     \
    for (int k = 0; k < 15; ++k){                                         \
      const float w0 = wp[k*64];                                          \
      const float w1 = wp[(k+15)*64];                                     \
      a0 = fmaf(na0[k],    w0, a0);                                       \
      a1 = fmaf(na0[k+15], w1, a1);                                       \
      b0 = fmaf(na1[k],    w0, b0);                                       \
      b1 = fmaf(na1[k+15], w1, b1);                                       \
      c0 = fmaf(na2[k],    w0, c0);                                       \
      c1 = fmaf(na2[k+15], w1, c1);                                       \
      d0 = fmaf(na3[k],    w0, d0);                                       \
      d1 = fmaf(na3[k+15], w1, d1);                                       \
    }                                                                     \
    u0 = a0 + a1; u1 = b0 + b1; u2 = c0 + c1; u3 = d0 + d1;               \
  }

// One tensor-product entry applied to the 4 nodes (literal indices only).
#define E4(DL,M,S)                                                        \
  {                                                                       \
    constexpr float cc_ = (float)cw_entry(DL,M,S);                        \
    o0[S] = fmaf(cc_ * u0, v0[M], o0[S]);                                 \
    o1[S] = fmaf(cc_ * u1, v1[M], o1[S]);                                 \
    o2[S] = fmaf(cc_ * u2, v2[M], o2[S]);                                 \
    o3[S] = fmaf(cc_ * u3, v3[M], o3[S]);                                 \
  }

__global__ __launch_bounds__(512)
void nn3b_main_kernel(const float* __restrict__ nbody,
                      const float* __restrict__ wcB,
                      const float* __restrict__ nab,
                      float* __restrict__ out)
{
  __shared__ __align__(16) float ldsw[5760];   // 23,040 B: one 3-dL chunk (R6 size)

  const int tid = threadIdx.x;
  const int c   = tid & 63;
  const int w   = __builtin_amdgcn_readfirstlane((int)(tid >> 6)); // 0..7
  const int n0  = blockIdx.x * 32 + w * 4;     // this wave's 4 nodes

  float o0[9] = {0,0,0,0,0,0,0,0,0};
  float o1[9] = {0,0,0,0,0,0,0,0,0};
  float o2[9] = {0,0,0,0,0,0,0,0,0};
  float o3[9] = {0,0,0,0,0,0,0,0,0};

  const float* na0 = nab + (size_t)(n0+0)*32;  // wave-uniform -> s_load
  const float* na1 = nab + (size_t)(n0+1)*32;
  const float* na2 = nab + (size_t)(n0+2)*32;
  const float* na3 = nab + (size_t)(n0+3)*32;

  #pragma unroll 1   // keep body-order loop rolled (R6 discipline)
  for (int b = 0; b < 3; ++b){
    float v0[9], v1[9], v2[9], v3[9];
    LD9(v0, nbody + ((size_t)b*N_NODES + n0+0)*576 + c*9);
    LD9(v1, nbody + ((size_t)b*N_NODES + n0+1)*576 + c*9);
    LD9(v2, nbody + ((size_t)b*N_NODES + n0+2)*576 + c*9);
    LD9(v3, nbody + ((size_t)b*N_NODES + n0+3)*576 + c*9);

    const float* wcb_b = wcB + b*(9*30*64);
    float u0, u1, u2, u3;

    STAGE(0)                                    // dL 0,1,2
    UCOMP4(0)
    E4(0,0,0) E4(0,1,1) E4(0,2,2) E4(0,3,3) E4(0,4,4) E4(0,5,5) E4(0,6,6) E4(0,7,7) E4(0,8,8)
    UCOMP4(1)
    E4(1,0,1) E4(1,1,0) E4(1,3,4) E4(1,2,5) E4(1,1,6) E4(1,1,8) E4(1,4,3) E4(1,5,2) E4(1,6,1) E4(1,8,1)
    UCOMP4(2)
    E4(2,0,2) E4(2,2,0) E4(2,1,5) E4(2,3,7) E4(2,2,6) E4(2,5,1) E4(2,7,3) E4(2,6,2)

    STAGE(1)                                    // dL 3,4,5
    UCOMP4(0)
    E4(3,0,3) E4(3,3,0) E4(3,1,4) E4(3,2,7) E4(3,3,6) E4(3,3,8) E4(3,4,1) E4(3,7,2) E4(3,6,3) E4(3,8,3)
    UCOMP4(1)
    E4(4,0,4) E4(4,4,0) E4(4,1,3) E4(4,3,1) E4(4,6,4) E4(4,4,6) E4(4,5,7) E4(4,7,5)
    UCOMP4(2)
    E4(5,0,5) E4(5,5,0) E4(5,1,2) E4(5,2,1) E4(5,6,5) E4(5,5,6) E4(5,5,8) E4(5,8,5) E4(5,4,7) E4(5,7,4)

    STAGE(2)                                    // dL 6,7,8
    UCOMP4(0)
    E4(6,0,6) E4(6,6,0) E4(6,1,1) E4(6,2,2) E4(6,3,3) E4(6,6,6) E4(6,5,5) E4(6,7,7) E4(6,4,4) E4(6,8,8)
    UCOMP4(1)
    E4(7,0,7) E4(7,7,0) E4(7,2,3) E4(7,3,2) E4(7,6,7) E4(7,7,6) E4(7,7,8) E4(7,8,7) E4(7,4,5) E4(7,5,4)
    UCOMP4(2)
    E4(8,0,8) E4(8,8,0) E4(8,1,1) E4(8,3,3) E4(8,6,8) E4(8,8,6) E4(8,5,5) E4(8,7,7)
  }

  ST9(out + (size_t)(n0+0)*576 + c*9, o0);
  ST9(out + (size_t)(n0+1)*576 + c*9, o1);
  ST9(out + (size_t)(n0+2)*576 + c*9, o2);
  ST9(out + (size_t)(n0+3)*576 + c*9, o3);
}

extern "C" void kernel_launch(void* const* d_in, const int* in_sizes, int n_in,
                              void* d_out, int out_size, void* d_ws, size_t ws_size,
                              hipStream_t stream)
{
  const float* nbody     = (const float*)d_in[0];  // (3, 20000, 64, 9) f32
  const float* node_attr = (const float*)d_in[1];  // (20000, 10) f32
  const float* W_chem    = (const float*)d_in[2];  // (30, 1728) f32
  const float* wbody     = (const float*)d_in[3];  // (3, 1) f32
  float* out = (float*)d_out;                      // (20000, 64, 9) f32

  float* wcB = (float*)d_ws;          // 51840 f
  float* nab = wcB + WCB_FLOATS;      // 640000 f   (total ~2.8 MiB of ws)

  const int init_items  = WCB_FLOATS + NAB_FLOATS;
  const int init_blocks = (init_items + 255) / 256;
  nn3b_init_kernel<<<init_blocks, 256, 0, stream>>>(node_attr, W_chem, wbody, wcB, nab);

  // 625 blocks x 32 nodes = 20000 exactly (no tail guards).
  nn3b_main_kernel<<<625, 512, 0, stream>>>(nbody, wcB, nab, out);
}

// Round 10
// 311.401 us; speedup vs baseline: 1.4342x; 1.0588x over previous
//
#include <hip/hip_runtime.h>

#define N_NODES 20000
#define WC4_FLOATS (3*9*2*4*64*4)      // 55296 = b128-quad-packed weights (k padded to 16/half)
#define NAB_FLOATS (N_NODES*32)        // 30 used per node, padded to 32

// ---------------------------------------------------------------------------
// Compile-time Wigner table (R6, unchanged): identical algorithm to the
// reference, evaluated as constexpr fp64; coefficients inlined as literals.
// ---------------------------------------------------------------------------
struct kx { double re, im; };

__host__ __device__ constexpr kx kmul(kx a, kx b){
  return { a.re*b.re - a.im*b.im, a.re*b.im + a.im*b.re };
}

__host__ __device__ constexpr double cfact(int n){
  double r = 1.0; for (int i = 2; i <= n; ++i) r *= (double)i; return r;
}

__host__ __device__ constexpr double csqrt(double x){
  if (x <= 0.0) return 0.0;
  double g = x > 1.0 ? x : 1.0;
  for (int i = 0; i < 64; ++i) g = 0.5*(g + x/g);   // converged fixed point
  return g;
}

__host__ __device__ constexpr double ccg(int j1,int m1,int j2,int m2,int j3,int m3){
  if (m3 != m1 + m2) return 0.0;
  int vmin = -j1 + j2 + m3;
  if (-j1 + m1 > vmin) vmin = -j1 + m1;
  if (vmin < 0) vmin = 0;
  int vmax = j2 + j3 + m1;
  if (j3 - j1 + j2 < vmax) vmax = j3 - j1 + j2;
  if (j3 + m3 < vmax) vmax = j3 + m3;
  double c = csqrt((double)(2*j3+1) *
      (cfact(j3+j1-j2)*cfact(j3-j1+j2)*cfact(j1+j2-j3)*cfact(j3+m3)*cfact(j3-m3)) /
      (cfact(j1+j2+j3+1)*cfact(j1-m1)*cfact(j1+m1)*cfact(j2-m2)*cfact(j2+m2)));
  double s = 0.0;
  for (int v = vmin; v <= vmax; ++v){
    double t = (cfact(j2+j3+m1-v)*cfact(j1-m1+v)) /
               (cfact(v)*cfact(j3-j1+j2-v)*cfact(j3+m3-v)*cfact(v+j1-j2-m3));
    s += ((v + j2 + m2) & 1) ? -t : t;
  }
  return c * s;
}

__host__ __device__ constexpr kx cq(int l, int r, int c){
  kx v = {0.0, 0.0};
  const double is2 = 0.70710678118654752440;
  const int m = r - l;
  if (m < 0){
    if (c == 2*l - r)      v = { is2, 0.0 };
    else if (c == r)       v = { 0.0, -is2 };
  } else if (m == 0){
    if (c == l)            v = { 1.0, 0.0 };
  } else {
    const double sg = (m & 1) ? -1.0 : 1.0;
    if (c == r)            v = { sg*is2, 0.0 };
    else if (c == 2*l - r) v = { 0.0, sg*is2 };
  }
  if (l == 1)      v = { v.im, -v.re };   // * (-i)
  else if (l == 2) v = { -v.re, -v.im };  // * (-i)^2 = -1
  return v;
}

__host__ __device__ constexpr double cw_entry(int L, int M, int S){
  const int l1 = (L==0)?0:((L<4)?1:2);
  const int l2 = (M==0)?0:((M<4)?1:2);
  const int l3 = (S==0)?0:((S<4)?1:2);
  const int a  = L - ((l1==0)?0:((l1==1)?1:4));
  const int b  = M - ((l2==0)?0:((l2==1)?1:4));
  const int cc = S - ((l3==0)?0:((l3==1)?1:4));
  const int lo = (l1 > l2) ? l1 - l2 : l2 - l1;
  if (!(l3 >= lo && l3 <= l1 + l2 && (((l1 + l2 + l3) & 1) == 0))) return 0.0;
  double ar = 0.0, ai = 0.0;
  for (int i = 0; i < 2*l1+1; ++i){
    kx q1 = cq(l1, i, a);
    if (q1.re == 0.0 && q1.im == 0.0) continue;
    for (int k = 0; k < 2*l2+1; ++k){
      kx q2 = cq(l2, k, b);
      if (q2.re == 0.0 && q2.im == 0.0) continue;
      kx q12 = kmul(q1, q2);
      for (int n = 0; n < 2*l3+1; ++n){
        kx q3 = cq(l3, n, cc);
        if (q3.re == 0.0 && q3.im == 0.0) continue;
        double cg = ccg(l1, i-l1, l2, k-l2, l3, n-l3);
        if (cg == 0.0) continue;
        kx q3c = { q3.re, -q3.im };
        kx term = kmul(q12, q3c);
        ar += term.re * cg;
        ai += term.im * cg;
      }
    }
  }
  const double w = ar / csqrt((double)(2*l3+1));
  return w * 0.10540925533894598;   // fold 1/sqrt(30)/sqrt(3)
}

// ---------------------------------------------------------------------------
// Init kernel: weights packed for ds_read_b128.
// wcb4 float index t = b*18432 + dL*2048 + h*1024 + jq*256 + c*4 + ji,
// h = half-chain (0: k=0..14, 1: k=15..29), slot s=jq*4+ji, k=h*15+s,
// s==15 -> 0.0f pad (fmaf(x,0,acc)==acc exactly -> chains bit-identical).
// nab: 32 floats/node, slots 30,31 = 0 (R6 layout, wave-uniform s_loads).
// ---------------------------------------------------------------------------
__global__ void nn3b_init_kernel(const float* __restrict__ node_attr,
                                 const float* __restrict__ W_chem,
                                 const float* __restrict__ wbody,
                                 float* __restrict__ wcb4,
                                 float* __restrict__ nab)
{
  const int t = blockIdx.x * 256 + threadIdx.x;

  if (t < WC4_FLOATS){
    const int ji = t & 3;
    const int c  = (t >> 2) & 63;
    const int jq = (t >> 8) & 3;
    const int h  = (t >> 10) & 1;
    const int dL = (t >> 11) % 9;
    const int b  = t / 18432;
    const int s  = jq*4 + ji;
    float v = 0.0f;
    if (s < 15){
      const int k = h*15 + s;
      v = W_chem[k*1728 + dL*192 + 3*c + b] * wbody[b];
    }
    wcb4[t] = v;
  }

  const int tc = t - WC4_FLOATS;
  if (tc >= 0 && tc < NAB_FLOATS){
    const int n = tc >> 5;
    const int k = tc & 31;
    float v = 0.0f;
    if (k < 30){
      const int i = 30*n + k;
      v = node_attr[(i % N_NODES)*10 + ((i / N_NODES) % 10)];
    }
    nab[tc] = v;
  }
}

// ---------------------------------------------------------------------------
// R15 main kernel: R6 structure (NP=2, 1250 blocks, full-occupancy codegen —
// the config that measured fastest at 150 us) + b128 weight reads.
// R14 post-mortem: halving LDS instrs via NP=4 cost occupancy (VGPR 104 ->
// 2 blocks/CU) and REGRESSED 150->183 us => kernel is latency-bound; TLP
// dominates. So: keep NP=2 registers (~90 VGPR, 4 blocks/CU) and cut
// per-wave LDS issue instead: 810 ds_read_b32 -> 216 ds_read_b128
// (27 dL-computations x 8 quads). fmaf order inside UCOMP identical to R6;
// pad slots multiply by 0.0 weights (exact no-ops) -> bit-identical output.
// ---------------------------------------------------------------------------
#define LD9(dst, p) { dst[0]=(p)[0]; dst[1]=(p)[1]; dst[2]=(p)[2];        \
                      dst[3]=(p)[3]; dst[4]=(p)[4]; dst[5]=(p)[5];        \
                      dst[6]=(p)[6]; dst[7]=(p)[7]; dst[8]=(p)[8]; }
#define ST9(p, src) { (p)[0]=src[0]; (p)[1]=src[1]; (p)[2]=src[2];        \
                      (p)[3]=src[3]; (p)[4]=src[4]; (p)[5]=src[5];        \
                      (p)[6]=src[6]; (p)[7]=src[7]; (p)[8]=src[8]; }

// Stage chunk Q (3 dL = 6144 floats = 1536 float4 = 24,576 B) into LDS.
#define STAGE(Q)                                                          \
  __syncthreads();                                                        \
  {                                                                       \
    const float4* s4 = (const float4*)wb + (Q)*1536;                      \
    float4* d4 = (float4*)ldsw;                                           \
    d4[tid]        = s4[tid];                                             \
    d4[tid + 512]  = s4[tid + 512];                                       \
    d4[tid + 1024] = s4[tid + 1024];                                      \
  }                                                                       \
  __syncthreads();

// One k-step of the dual-node dual-half chain (R6's exact fmaf order).
#define UK(K, Q0, E0, Q1, E1)                                             \
  a0 = fmaf(naA[K],    Q0.E0, a0);                                        \
  a1 = fmaf(naA[K+15], Q1.E1, a1);                                        \
  b0 = fmaf(naB[K],    Q0.E0, b0);                                        \
  b1 = fmaf(naB[K+15], Q1.E1, b1);

// u for local dL slot DLL (0..2): 8 ds_read_b128 (named quads, literal
// offsets), then 15 UK steps in R6's k order. u = a-chain + b-chain.
#define UCOMP2Q(DLL)                                                      \
  {                                                                       \
    const float4* l4 = (const float4*)ldsw + (DLL)*512 + c;               \
    const float4 q0 = l4[0],   q1 = l4[64],  q2 = l4[128], q3 = l4[192];  \
    const float4 q4 = l4[256], q5 = l4[320], q6 = l4[384], q7 = l4[448];  \
    float a0=0.f, a1=0.f, b0=0.f, b1=0.f;                                 \
    UK( 0,q0,x,q4,x) UK( 1,q0,y,q4,y) UK( 2,q0,z,q4,z) UK( 3,q0,w,q4,w)   \
    UK( 4,q1,x,q5,x) UK( 5,q1,y,q5,y) UK( 6,q1,z,q5,z) UK( 7,q1,w,q5,w)   \
    UK( 8,q2,x,q6,x) UK( 9,q2,y,q6,y) UK(10,q2,z,q6,z) UK(11,q2,w,q6,w)   \
    UK(12,q3,x,q7,x) UK(13,q3,y,q7,y) UK(14,q3,z,q7,z)                    \
    uA = a0 + a1; uB = b0 + b1;                                           \
  }

// One tensor-product entry: o[S] += cw(DL,M,S) * u * v[M]  (literal indices)
#define E(DL,M,S)                                                         \
  {                                                                       \
    constexpr float cc_ = (float)cw_entry(DL,M,S);                        \
    oA[S] = fmaf(cc_ * uA, vA[M], oA[S]);                                 \
    oB[S] = fmaf(cc_ * uB, vB[M], oB[S]);                                 \
  }

__global__ __launch_bounds__(512)
void nn3b_main_kernel(const float* __restrict__ nbody,
                      const float* __restrict__ wcb4,
                      const float* __restrict__ nab,
                      float* __restrict__ out)
{
  __shared__ __align__(16) float ldsw[6144];   // 24,576 B: one 3-dL quad chunk

  const int tid = threadIdx.x;
  const int c   = tid & 63;
  const int g   = __builtin_amdgcn_readfirstlane((int)(tid >> 6)); // 0..7
  const int nA  = blockIdx.x * 16 + g * 2;     // this wave's node pair (R6)
  const int nB  = nA + 1;

  float oA[9] = {0,0,0,0,0,0,0,0,0};
  float oB[9] = {0,0,0,0,0,0,0,0,0};

  const float* naA = nab + (size_t)nA * 32;    // wave-uniform -> s_load
  const float* naB = nab + (size_t)nB * 32;

  #pragma unroll 1   // keep body-order loop rolled (R6 discipline)
  for (int b = 0; b < 3; ++b){
    float vA[9], vB[9];
    LD9(vA, nbody + ((size_t)b*N_NODES + nA)*576 + c*9);
    LD9(vB, nbody + ((size_t)b*N_NODES + nB)*576 + c*9);

    const float* wb = wcb4 + b*18432;
    float uA, uB;

    STAGE(0)                                    // dL 0,1,2
    UCOMP2Q(0)
    E(0,0,0) E(0,1,1) E(0,2,2) E(0,3,3) E(0,4,4) E(0,5,5) E(0,6,6) E(0,7,7) E(0,8,8)
    UCOMP2Q(1)
    E(1,0,1) E(1,1,0) E(1,3,4) E(1,2,5) E(1,1,6) E(1,1,8) E(1,4,3) E(1,5,2) E(1,6,1) E(1,8,1)
    UCOMP2Q(2)
    E(2,0,2) E(2,2,0) E(2,1,5) E(2,3,7) E(2,2,6) E(2,5,1) E(2,7,3) E(2,6,2)

    STAGE(1)                                    // dL 3,4,5
    UCOMP2Q(0)
    E(3,0,3) E(3,3,0) E(3,1,4) E(3,2,7) E(3,3,6) E(3,3,8) E(3,4,1) E(3,7,2) E(3,6,3) E(3,8,3)
    UCOMP2Q(1)
    E(4,0,4) E(4,4,0) E(4,1,3) E(4,3,1) E(4,6,4) E(4,4,6) E(4,5,7) E(4,7,5)
    UCOMP2Q(2)
    E(5,0,5) E(5,5,0) E(5,1,2) E(5,2,1) E(5,6,5) E(5,5,6) E(5,5,8) E(5,8,5) E(5,4,7) E(5,7,4)

    STAGE(2)                                    // dL 6,7,8
    UCOMP2Q(0)
    E(6,0,6) E(6,6,0) E(6,1,1) E(6,2,2) E(6,3,3) E(6,6,6) E(6,5,5) E(6,7,7) E(6,4,4) E(6,8,8)
    UCOMP2Q(1)
    E(7,0,7) E(7,7,0) E(7,2,3) E(7,3,2) E(7,6,7) E(7,7,6) E(7,7,8) E(7,8,7) E(7,4,5) E(7,5,4)
    UCOMP2Q(2)
    E(8,0,8) E(8,8,0) E(8,1,1) E(8,3,3) E(8,6,8) E(8,8,6) E(8,5,5) E(8,7,7)
  }

  ST9(out + (size_t)nA*576 + c*9, oA);
  ST9(out + (size_t)nB*576 + c*9, oB);
}

extern "C" void kernel_launch(void* const* d_in, const int* in_sizes, int n_in,
                              void* d_out, int out_size, void* d_ws, size_t ws_size,
                              hipStream_t stream)
{
  const float* nbody     = (const float*)d_in[0];  // (3, 20000, 64, 9) f32
  const float* node_attr = (const float*)d_in[1];  // (20000, 10) f32
  const float* W_chem    = (const float*)d_in[2];  // (30, 1728) f32
  const float* wbody     = (const float*)d_in[3];  // (3, 1) f32
  float* out = (float*)d_out;                      // (20000, 64, 9) f32

  float* wcb4 = (float*)d_ws;          // 55296 f
  float* nab  = wcb4 + WC4_FLOATS;     // 640000 f   (total ~2.78 MiB of ws)

  const int init_items  = WC4_FLOATS + NAB_FLOATS;
  const int init_blocks = (init_items + 255) / 256;
  nn3b_init_kernel<<<init_blocks, 256, 0, stream>>>(node_attr, W_chem, wbody, wcb4, nab);

  // R6 grid: 1250 blocks x 16 nodes, 2 nodes/wave (full-occupancy config).
  nn3b_main_kernel<<<N_NODES/16, 512, 0, stream>>>(nbody, wcb4, nab, out);
}